// Round 3
// baseline (379.000 us; speedup 1.0000x reference)
//
#include <hip/hip_runtime.h>
#include <hip/hip_bf16.h>
#include <math.h>

typedef __attribute__((ext_vector_type(8))) __bf16 bf16x8;
typedef __attribute__((ext_vector_type(4))) float f32x4;
typedef __attribute__((ext_vector_type(4))) unsigned short u16x4;

#define TOKENS 32768
#define CDIM   768     // model dim = N of fc2, K of fc1
#define NKDIM  768     // 4 experts * 192 = N of fc1, K of fc2

// async global->LDS, 16B per lane; LDS dest is wave-uniform base + lane*16
__device__ __forceinline__ void async_copy16(const void* g, void* l) {
    __builtin_amdgcn_global_load_lds(
        (const __attribute__((address_space(1))) void*)g,
        (__attribute__((address_space(3))) void*)l, 16, 0, 0);
}

// ---------------- weight prep: fp32 -> bf16, fc2 transposed to [c][e*192+h] ----
__global__ __launch_bounds__(256) void prep_weights(
    const float* __restrict__ fc1w, const float* __restrict__ fc2w,
    __hip_bfloat16* __restrict__ b1, __hip_bfloat16* __restrict__ b2t)
{
    int idx = blockIdx.x * 256 + threadIdx.x;
    if (idx >= 768 * 768) return;
    // b1[n][k] = fc1_w[e][h][c] with n=e*192+h, k=c  -> flat identity
    b1[idx] = __float2bfloat16(fc1w[idx]);
    // b2t[c][e*192+h] = fc2_w[e][c][h]
    int c = idx / 768;
    int r = idx - c * 768;
    int e = r / 192;
    int h = r - e * 192;
    b2t[idx] = __float2bfloat16(fc2w[((size_t)e * 768 + c) * 192 + h]);
}

// ---------------- router + x fp32->bf16 conversion: one wave per token --------
__global__ __launch_bounds__(256) void router_convert(
    const float* __restrict__ x, const float* __restrict__ rw,
    const float* __restrict__ rb,
    __hip_bfloat16* __restrict__ xb, float* __restrict__ comb)
{
    int wave = threadIdx.x >> 6;
    int lane = threadIdx.x & 63;
    int token = blockIdx.x * 4 + wave;

    const float* xr = x + (size_t)token * CDIM + lane * 12;
    float4 v0 = *(const float4*)(xr);
    float4 v1 = *(const float4*)(xr + 4);
    float4 v2 = *(const float4*)(xr + 8);

    // convert + store bf16 copy of x
    float vals[12];
    *(float4*)(vals) = v0; *(float4*)(vals + 4) = v1; *(float4*)(vals + 8) = v2;
    alignas(16) __hip_bfloat16 hb[12];
#pragma unroll
    for (int j = 0; j < 12; ++j) hb[j] = __float2bfloat16(vals[j]);
    u16x4* dst = (u16x4*)((unsigned short*)xb + (size_t)token * CDIM + lane * 12);
    dst[0] = ((u16x4*)hb)[0];
    dst[1] = ((u16x4*)hb)[1];
    dst[2] = ((u16x4*)hb)[2];

    // router logits: 4 dots of length 768 (fp32, matches reference precision)
    float s[4];
#pragma unroll
    for (int e = 0; e < 4; ++e) {
        const float* w = rw + e * CDIM + lane * 12;
        float4 w0 = *(const float4*)(w);
        float4 w1 = *(const float4*)(w + 4);
        float4 w2 = *(const float4*)(w + 8);
        s[e] = v0.x * w0.x + v0.y * w0.y + v0.z * w0.z + v0.w * w0.w
             + v1.x * w1.x + v1.y * w1.y + v1.z * w1.z + v1.w * w1.w
             + v2.x * w2.x + v2.y * w2.y + v2.z * w2.z + v2.w * w2.w;
    }
#pragma unroll
    for (int e = 0; e < 4; ++e) {
        float v = s[e];
        v += __shfl_xor(v, 32); v += __shfl_xor(v, 16); v += __shfl_xor(v, 8);
        v += __shfl_xor(v, 4);  v += __shfl_xor(v, 2);  v += __shfl_xor(v, 1);
        s[e] = v;
    }
    // softmax over 4 + top-2 + renormalize (all lanes compute, lane 0 writes)
    float lg[4], p[4];
#pragma unroll
    for (int e = 0; e < 4; ++e) lg[e] = s[e] + rb[e];
    float mx = fmaxf(fmaxf(lg[0], lg[1]), fmaxf(lg[2], lg[3]));
    float ps = 0.f;
#pragma unroll
    for (int e = 0; e < 4; ++e) { p[e] = __expf(lg[e] - mx); ps += p[e]; }
#pragma unroll
    for (int e = 0; e < 4; ++e) p[e] /= ps;
    int a = 0;
#pragma unroll
    for (int e = 1; e < 4; ++e) if (p[e] > p[a]) a = e;   // ties -> first (jax)
    int b = (a == 0) ? 1 : 0;
#pragma unroll
    for (int e = 0; e < 4; ++e) if (e != a && p[e] > p[b]) b = e;
    float wsum = p[a] + p[b] + 1e-8f;
    float cb[4] = {0.f, 0.f, 0.f, 0.f};
    cb[a] = p[a] / wsum;
    cb[b] = p[b] / wsum;
    if (lane == 0) {
        float4 o; o.x = cb[0]; o.y = cb[1]; o.z = cb[2]; o.w = cb[3];
        *(float4*)(comb + (size_t)token * 4) = o;
    }
}

// ---------------- GEMM C = A[M x K] * Bt[N x K]^T with fused MoE epilogues ----
// m97 structure + XCD-aware block swizzle + XOR'd LDS granules.
// MODE 0: fc1  -> hw[t][n] = bf16( gelu(acc + fc1_b[n]) * combine[t][n/192] )
// MODE 1: fc2  -> out[t][c] = acc + sum_e combine[t][e] * fc2_b[e][c]
#define BM 128
#define BN 128
#define BK 64

template <int MODE, int K>
__global__ __launch_bounds__(256) void gemm_bt(
    const __hip_bfloat16* __restrict__ A, const __hip_bfloat16* __restrict__ Bt,
    const float* __restrict__ comb,
    const float* __restrict__ bias1,   // fc1_b flat [768] (MODE 0)
    const float* __restrict__ bias2,   // fc2_b [4][768]   (MODE 1)
    __hip_bfloat16* __restrict__ HW,   // MODE 0 output
    float* __restrict__ OUT)           // MODE 1 output
{
    // As = smem[0 : BM*BK), Bs = smem[BM*BK : 2*BM*BK); 32 KB total.
    // LDS layout: row-major rows of BK, but 16B granule g of row r lives at
    // physical granule g ^ (r & 7)  -> fragment reads spread 8 banks (2-way, free)
    __shared__ __hip_bfloat16 smem[BM * BK * 2];
    __hip_bfloat16* As = smem;
    __hip_bfloat16* Bs = smem + BM * BK;

    const int tid = threadIdx.x;
    const int wave = tid >> 6, lane = tid & 63;
    const int wm = (wave >> 1) * 64, wn = (wave & 1) * 64;
    const int lrow = lane & 15, quad = lane >> 4;

    // XCD-aware swizzle: flat grid 1536 = 8 XCDs x 32 M-tiles x 6 N-tiles.
    // All 6 N-blocks sharing an A-tile get the same (id&7) -> same XCD,
    // adjacent slots -> temporally co-resident -> A fetched once per XCD band.
    {
    }
    const int g = blockIdx.x;
    const int xcd = g & 7;
    const int slot = g >> 3;            // 0..191
    const int byg = slot / 6;           // 0..31
    const int bx = slot - byg * 6;      // 0..5
    const int by = (xcd << 5) + byg;    // 0..255
    const int rowB0 = bx * BN;
    const int rowA0 = by * BM;

    // staging map: chunk c covers rows [8c, 8c+8), 1 KiB contiguous in LDS.
    // lane i -> slot (row 8c+(i>>3), phys granule i&7); fetch global granule
    // (i&7) ^ row_in_chunk so that phys = logical ^ (row&7).
    const int srow = lane >> 3;                 // 0..7 row within chunk
    const int scol = ((lane & 7) ^ srow) * 8;   // source granule (elements)

    f32x4 acc[4][4] = {};

    for (int k0 = 0; k0 < K; k0 += BK) {
        const __hip_bfloat16* Ab = A + (size_t)rowA0 * K + k0;
        const __hip_bfloat16* Bb = Bt + (size_t)rowB0 * K + k0;
#pragma unroll
        for (int p = 0; p < 4; ++p) {
            int c = wave * 4 + p;               // chunk 0..15
            int row = c * 8 + srow;
            async_copy16(Ab + (size_t)row * K + scol, As + c * 8 * BK);
            async_copy16(Bb + (size_t)row * K + scol, Bs + c * 8 * BK);
        }
        __syncthreads();
#pragma unroll
        for (int kk = 0; kk < BK; kk += 32) {
            bf16x8 af[4], bfr[4];
#pragma unroll
            for (int i = 0; i < 4; ++i) {
                int row = wm + i * 16 + lrow;
                int gp = ((kk >> 3) + quad) ^ (lrow & 7);
                af[i] = *(const bf16x8*)(&As[row * BK + gp * 8]);
            }
#pragma unroll
            for (int j = 0; j < 4; ++j) {
                int row = wn + j * 16 + lrow;
                int gp = ((kk >> 3) + quad) ^ (lrow & 7);
                bfr[j] = *(const bf16x8*)(&Bs[row * BK + gp * 8]);
            }
#pragma unroll
            for (int i = 0; i < 4; ++i)
#pragma unroll
                for (int j = 0; j < 4; ++j)
                    acc[i][j] = __builtin_amdgcn_mfma_f32_16x16x32_bf16(
                        af[i], bfr[j], acc[i][j], 0, 0, 0);
        }
        __syncthreads();
    }

    // epilogue; C/D layout: col = lane&15, row = quad*4 + reg  [verified m89/m91]
    if (MODE == 0) {
        // compute gelu*combine, write bf16 into LDS tile, then coalesced store
#pragma unroll
        for (int i = 0; i < 4; ++i) {
#pragma unroll
            for (int j = 0; j < 4; ++j) {
                int coll = wn + j * 16 + lrow;
                int e = (rowB0 + wn + j * 16) / 192;  // uniform per j (16 | 192)
                float bias = bias1[rowB0 + coll];
#pragma unroll
                for (int r = 0; r < 4; ++r) {
                    int rowl = wm + i * 16 + quad * 4 + r;
                    float v = acc[i][j][r] + bias;
                    v = 0.5f * v * (1.0f + erff(v * 0.70710678118654752f));
                    v *= comb[(size_t)(rowA0 + rowl) * 4 + e];
                    smem[rowl * BN + coll] = __float2bfloat16(v);
                }
            }
        }
        __syncthreads();
        // 128 rows x 256 B; 2048 uint4 chunks over 256 threads = 8 each
#pragma unroll
        for (int t = 0; t < 8; ++t) {
            int idx = t * 256 + tid;
            int row = idx >> 4;            // 0..127
            int c16 = (idx & 15) * 8;      // element col, 16B granules
            *(uint4*)(HW + (size_t)(rowA0 + row) * NKDIM + rowB0 + c16) =
                *(const uint4*)(&smem[row * BN + c16]);
        }
    } else {
#pragma unroll
        for (int i = 0; i < 4; ++i) {
#pragma unroll
            for (int j = 0; j < 4; ++j) {
                int col = rowB0 + wn + j * 16 + lrow;
#pragma unroll
                for (int r = 0; r < 4; ++r) {
                    int row = rowA0 + wm + i * 16 + quad * 4 + r;
                    float v = acc[i][j][r];
                    float4 cw = *(const float4*)(comb + (size_t)row * 4);
                    v += cw.x * bias2[col] + cw.y * bias2[768 + col]
                       + cw.z * bias2[1536 + col] + cw.w * bias2[2304 + col];
                    OUT[(size_t)row * CDIM + col] = v;
                }
            }
        }
    }
}

extern "C" void kernel_launch(void* const* d_in, const int* in_sizes, int n_in,
                              void* d_out, int out_size, void* d_ws, size_t ws_size,
                              hipStream_t stream)
{
    const float* x    = (const float*)d_in[0];
    const float* rw   = (const float*)d_in[1];
    const float* rb   = (const float*)d_in[2];
    const float* fc1w = (const float*)d_in[3];
    const float* fc1b = (const float*)d_in[4];
    const float* fc2w = (const float*)d_in[5];
    const float* fc2b = (const float*)d_in[6];
    float* out = (float*)d_out;

    // workspace layout (bytes), all 16B-aligned; total ~103.6 MB
    char* ws = (char*)d_ws;
    __hip_bfloat16* xb  = (__hip_bfloat16*)(ws);                 // 32768*768*2 = 50331648
    __hip_bfloat16* hw  = (__hip_bfloat16*)(ws + 50331648);      // 50331648
    __hip_bfloat16* b1  = (__hip_bfloat16*)(ws + 100663296);     // 1179648
    __hip_bfloat16* b2t = (__hip_bfloat16*)(ws + 101842944);     // 1179648
    float*          cmb = (float*)        (ws + 103022592);      // 524288

    prep_weights<<<2304, 256, 0, stream>>>(fc1w, fc2w, b1, b2t);
    router_convert<<<TOKENS / 4, 256, 0, stream>>>(x, rw, rb, xb, cmb);

    int nblocks = (NKDIM / BN) * (TOKENS / BM);   // 1536, XCD-swizzled in-kernel
    gemm_bt<0, CDIM><<<nblocks, 256, 0, stream>>>(xb, b1, cmb, fc1b, nullptr, hw, nullptr);
    gemm_bt<1, NKDIM><<<nblocks, 256, 0, stream>>>(hw, b2t, cmb, nullptr, fc2b, nullptr, out);
}

// Round 4
// 328.594 us; speedup vs baseline: 1.1534x; 1.1534x over previous
//
#include <hip/hip_runtime.h>
#include <hip/hip_bf16.h>
#include <math.h>

typedef __attribute__((ext_vector_type(8))) __bf16 bf16x8;
typedef __attribute__((ext_vector_type(4))) float f32x4;
typedef __attribute__((ext_vector_type(4))) unsigned short u16x4;

#define TOKENS 32768
#define CDIM   768     // model dim = N of fc2, K of fc1
#define NKDIM  768     // 4 experts * 192 = N of fc1, K of fc2

// async global->LDS, 16B per lane; LDS dest is wave-uniform base + lane*16
__device__ __forceinline__ void async_copy16(const void* g, void* l) {
    __builtin_amdgcn_global_load_lds(
        (const __attribute__((address_space(1))) void*)g,
        (__attribute__((address_space(3))) void*)l, 16, 0, 0);
}

// ---------------- weight prep: fp32 -> bf16, fc2 transposed to [c][e*192+h] ----
__global__ __launch_bounds__(256) void prep_weights(
    const float* __restrict__ fc1w, const float* __restrict__ fc2w,
    __hip_bfloat16* __restrict__ b1, __hip_bfloat16* __restrict__ b2t)
{
    int idx = blockIdx.x * 256 + threadIdx.x;
    if (idx >= 768 * 768) return;
    // b1[n][k] = fc1_w[e][h][c] with n=e*192+h, k=c  -> flat identity
    b1[idx] = __float2bfloat16(fc1w[idx]);
    // b2t[c][e*192+h] = fc2_w[e][c][h]
    int c = idx / 768;
    int r = idx - c * 768;
    int e = r / 192;
    int h = r - e * 192;
    b2t[idx] = __float2bfloat16(fc2w[((size_t)e * 768 + c) * 192 + h]);
}

// ---------------- router + x fp32->bf16 conversion: one wave per token --------
__global__ __launch_bounds__(256) void router_convert(
    const float* __restrict__ x, const float* __restrict__ rw,
    const float* __restrict__ rb,
    __hip_bfloat16* __restrict__ xb, float* __restrict__ comb)
{
    int wave = threadIdx.x >> 6;
    int lane = threadIdx.x & 63;
    int token = blockIdx.x * 4 + wave;

    const float* xr = x + (size_t)token * CDIM + lane * 12;
    float4 v0 = *(const float4*)(xr);
    float4 v1 = *(const float4*)(xr + 4);
    float4 v2 = *(const float4*)(xr + 8);

    // convert + store bf16 copy of x
    float vals[12];
    *(float4*)(vals) = v0; *(float4*)(vals + 4) = v1; *(float4*)(vals + 8) = v2;
    alignas(16) __hip_bfloat16 hb[12];
#pragma unroll
    for (int j = 0; j < 12; ++j) hb[j] = __float2bfloat16(vals[j]);
    u16x4* dst = (u16x4*)((unsigned short*)xb + (size_t)token * CDIM + lane * 12);
    dst[0] = ((u16x4*)hb)[0];
    dst[1] = ((u16x4*)hb)[1];
    dst[2] = ((u16x4*)hb)[2];

    // router logits: 4 dots of length 768 (fp32, matches reference precision)
    float s[4];
#pragma unroll
    for (int e = 0; e < 4; ++e) {
        const float* w = rw + e * CDIM + lane * 12;
        float4 w0 = *(const float4*)(w);
        float4 w1 = *(const float4*)(w + 4);
        float4 w2 = *(const float4*)(w + 8);
        s[e] = v0.x * w0.x + v0.y * w0.y + v0.z * w0.z + v0.w * w0.w
             + v1.x * w1.x + v1.y * w1.y + v1.z * w1.z + v1.w * w1.w
             + v2.x * w2.x + v2.y * w2.y + v2.z * w2.z + v2.w * w2.w;
    }
#pragma unroll
    for (int e = 0; e < 4; ++e) {
        float v = s[e];
        v += __shfl_xor(v, 32); v += __shfl_xor(v, 16); v += __shfl_xor(v, 8);
        v += __shfl_xor(v, 4);  v += __shfl_xor(v, 2);  v += __shfl_xor(v, 1);
        s[e] = v;
    }
    // softmax over 4 + top-2 + renormalize (all lanes compute, lane 0 writes)
    float lg[4], p[4];
#pragma unroll
    for (int e = 0; e < 4; ++e) lg[e] = s[e] + rb[e];
    float mx = fmaxf(fmaxf(lg[0], lg[1]), fmaxf(lg[2], lg[3]));
    float ps = 0.f;
#pragma unroll
    for (int e = 0; e < 4; ++e) { p[e] = __expf(lg[e] - mx); ps += p[e]; }
#pragma unroll
    for (int e = 0; e < 4; ++e) p[e] /= ps;
    int a = 0;
#pragma unroll
    for (int e = 1; e < 4; ++e) if (p[e] > p[a]) a = e;   // ties -> first (jax)
    int b = (a == 0) ? 1 : 0;
#pragma unroll
    for (int e = 0; e < 4; ++e) if (e != a && p[e] > p[b]) b = e;
    float wsum = p[a] + p[b] + 1e-8f;
    float cb[4] = {0.f, 0.f, 0.f, 0.f};
    cb[a] = p[a] / wsum;
    cb[b] = p[b] / wsum;
    if (lane == 0) {
        float4 o; o.x = cb[0]; o.y = cb[1]; o.z = cb[2]; o.w = cb[3];
        *(float4*)(comb + (size_t)token * 4) = o;
    }
}

// ---------------- GEMM C = A[M x K] * Bt[N x K]^T with fused MoE epilogues ----
// m97 staging + XCD-aware swizzle + XOR'd LDS granules + double-buffered
// prefetch: iter k+1's global_load_lds issued before iter k's compute, so the
// barrier drain at iter end only pays the latency remainder (1-deep pipeline).
// MODE 0: fc1  -> hw[t][n] = bf16( gelu(acc + fc1_b[n]) * combine[t][n/192] )
// MODE 1: fc2  -> out[t][c] = acc + sum_e combine[t][e] * fc2_b[e][c]
#define BM 128
#define BN 128
#define BK 64

template <int MODE, int K>
__global__ __launch_bounds__(256) void gemm_bt(
    const __hip_bfloat16* __restrict__ A, const __hip_bfloat16* __restrict__ Bt,
    const float* __restrict__ comb,
    const float* __restrict__ bias1,   // fc1_b flat [768] (MODE 0)
    const float* __restrict__ bias2,   // fc2_b [4][768]   (MODE 1)
    __hip_bfloat16* __restrict__ HW,   // MODE 0 output
    float* __restrict__ OUT)           // MODE 1 output
{
    // two (A,B) buffers: buf b at smem + b*2*BM*BK; 64 KB total.
    // 16B granule g of row r lives at physical granule g ^ (r & 7).
    __shared__ __hip_bfloat16 smem[BM * BK * 4];

    const int tid = threadIdx.x;
    const int wave = tid >> 6, lane = tid & 63;
    const int wm = (wave >> 1) * 64, wn = (wave & 1) * 64;
    const int lrow = lane & 15, quad = lane >> 4;

    // XCD-aware swizzle: flat grid 1536 = 8 XCDs x 32 M-tiles x 6 N-tiles.
    const int g = blockIdx.x;
    const int xcd = g & 7;
    const int slot = g >> 3;            // 0..191
    const int byg = slot / 6;           // 0..31
    const int bx = slot - byg * 6;      // 0..5
    const int by = (xcd << 5) + byg;    // 0..255
    const int rowB0 = bx * BN;
    const int rowA0 = by * BM;

    const int srow = lane >> 3;                 // 0..7 row within chunk
    const int scol = ((lane & 7) ^ srow) * 8;   // source granule (elements)

    const __hip_bfloat16* Abase = A + (size_t)rowA0 * K;
    const __hip_bfloat16* Bbase = Bt + (size_t)rowB0 * K;

    auto stage = [&](int buf, int k0) {
        __hip_bfloat16* As = smem + buf * (2 * BM * BK);
        __hip_bfloat16* Bs = As + BM * BK;
#pragma unroll
        for (int p = 0; p < 4; ++p) {
            int c = wave * 4 + p;               // chunk 0..15
            int row = c * 8 + srow;
            async_copy16(Abase + (size_t)row * K + k0 + scol, As + c * 8 * BK);
            async_copy16(Bbase + (size_t)row * K + k0 + scol, Bs + c * 8 * BK);
        }
    };

    f32x4 acc[4][4] = {};
    constexpr int NIT = K / BK;     // 12

    stage(0, 0);
    __syncthreads();
#pragma unroll
    for (int it = 0; it < NIT; ++it) {
        if (it + 1 < NIT) stage((it + 1) & 1, (it + 1) * BK);  // prefetch in flight
        const __hip_bfloat16* As = smem + (it & 1) * (2 * BM * BK);
        const __hip_bfloat16* Bs = As + BM * BK;
#pragma unroll
        for (int kk = 0; kk < BK; kk += 32) {
            bf16x8 af[4], bfr[4];
#pragma unroll
            for (int i = 0; i < 4; ++i) {
                int row = wm + i * 16 + lrow;
                int gp = ((kk >> 3) + quad) ^ (lrow & 7);
                af[i] = *(const bf16x8*)(&As[row * BK + gp * 8]);
            }
#pragma unroll
            for (int j = 0; j < 4; ++j) {
                int row = wn + j * 16 + lrow;
                int gp = ((kk >> 3) + quad) ^ (lrow & 7);
                bfr[j] = *(const bf16x8*)(&Bs[row * BK + gp * 8]);
            }
#pragma unroll
            for (int i = 0; i < 4; ++i)
#pragma unroll
                for (int j = 0; j < 4; ++j)
                    acc[i][j] = __builtin_amdgcn_mfma_f32_16x16x32_bf16(
                        af[i], bfr[j], acc[i][j], 0, 0, 0);
        }
        __syncthreads();   // drains prefetch (vmcnt 0) + guards LDS reuse
    }

    // epilogue; C/D layout: col = lane&15, row = quad*4 + reg  [verified m89/m91]
    if (MODE == 0) {
        // compute gelu*combine, write bf16 into LDS tile (first 32 KB), store wide
#pragma unroll
        for (int i = 0; i < 4; ++i) {
#pragma unroll
            for (int j = 0; j < 4; ++j) {
                int coll = wn + j * 16 + lrow;
                int e = (rowB0 + wn + j * 16) / 192;  // uniform per j (16 | 192)
                float bias = bias1[rowB0 + coll];
#pragma unroll
                for (int r = 0; r < 4; ++r) {
                    int rowl = wm + i * 16 + quad * 4 + r;
                    float v = acc[i][j][r] + bias;
                    v = 0.5f * v * (1.0f + erff(v * 0.70710678118654752f));
                    v *= comb[(size_t)(rowA0 + rowl) * 4 + e];
                    smem[rowl * BN + coll] = __float2bfloat16(v);
                }
            }
        }
        __syncthreads();
        // 128 rows x 256 B; 2048 uint4 chunks over 256 threads = 8 each
#pragma unroll
        for (int t = 0; t < 8; ++t) {
            int idx = t * 256 + tid;
            int row = idx >> 4;            // 0..127
            int c16 = (idx & 15) * 8;      // element col, 16B granules
            *(uint4*)(HW + (size_t)(rowA0 + row) * NKDIM + rowB0 + c16) =
                *(const uint4*)(&smem[row * BN + c16]);
        }
    } else {
#pragma unroll
        for (int i = 0; i < 4; ++i) {
#pragma unroll
            for (int r = 0; r < 4; ++r) {
                int row = rowA0 + wm + i * 16 + quad * 4 + r;
                float4 cw = *(const float4*)(comb + (size_t)row * 4);  // hoisted per row
#pragma unroll
                for (int j = 0; j < 4; ++j) {
                    int col = rowB0 + wn + j * 16 + lrow;
                    float v = acc[i][j][r];
                    v += cw.x * bias2[col] + cw.y * bias2[768 + col]
                       + cw.z * bias2[1536 + col] + cw.w * bias2[2304 + col];
                    OUT[(size_t)row * CDIM + col] = v;
                }
            }
        }
    }
}

extern "C" void kernel_launch(void* const* d_in, const int* in_sizes, int n_in,
                              void* d_out, int out_size, void* d_ws, size_t ws_size,
                              hipStream_t stream)
{
    const float* x    = (const float*)d_in[0];
    const float* rw   = (const float*)d_in[1];
    const float* rb   = (const float*)d_in[2];
    const float* fc1w = (const float*)d_in[3];
    const float* fc1b = (const float*)d_in[4];
    const float* fc2w = (const float*)d_in[5];
    const float* fc2b = (const float*)d_in[6];
    float* out = (float*)d_out;

    // workspace layout (bytes), all 16B-aligned; total ~103.6 MB
    char* ws = (char*)d_ws;
    __hip_bfloat16* xb  = (__hip_bfloat16*)(ws);                 // 32768*768*2 = 50331648
    __hip_bfloat16* hw  = (__hip_bfloat16*)(ws + 50331648);      // 50331648
    __hip_bfloat16* b1  = (__hip_bfloat16*)(ws + 100663296);     // 1179648
    __hip_bfloat16* b2t = (__hip_bfloat16*)(ws + 101842944);     // 1179648
    float*          cmb = (float*)        (ws + 103022592);      // 524288

    prep_weights<<<2304, 256, 0, stream>>>(fc1w, fc2w, b1, b2t);
    router_convert<<<TOKENS / 4, 256, 0, stream>>>(x, rw, rb, xb, cmb);

    int nblocks = (NKDIM / BN) * (TOKENS / BM);   // 1536, XCD-swizzled in-kernel
    gemm_bt<0, CDIM><<<nblocks, 256, 0, stream>>>(xb, b1, cmb, fc1b, nullptr, hw, nullptr);
    gemm_bt<1, NKDIM><<<nblocks, 256, 0, stream>>>(hw, b2t, cmb, nullptr, fc2b, nullptr, out);
}

// Round 5
// 292.853 us; speedup vs baseline: 1.2942x; 1.1220x over previous
//
#include <hip/hip_runtime.h>
#include <hip/hip_bf16.h>
#include <math.h>

typedef __attribute__((ext_vector_type(8))) __bf16 bf16x8;
typedef __attribute__((ext_vector_type(4))) float f32x4;
typedef __attribute__((ext_vector_type(4))) unsigned short u16x4;

#define TOKENS 32768
#define CDIM   768     // model dim = N of fc2, K of fc1
#define NKDIM  768     // 4 experts * 192 = N of fc1, K of fc2

// async global->LDS, 16B per lane; LDS dest is wave-uniform base + lane*16
__device__ __forceinline__ void async_copy16(const void* g, void* l) {
    __builtin_amdgcn_global_load_lds(
        (const __attribute__((address_space(1))) void*)g,
        (__attribute__((address_space(3))) void*)l, 16, 0, 0);
}

// exact-GELU via A&S 7.1.26 erf approx, |erf err| < 1.5e-7 (far below bf16 eps)
__device__ __forceinline__ float fast_gelu(float v) {
    float x  = v * 0.70710678118654752f;
    float ax = fabsf(x);
    float t  = __builtin_amdgcn_rcpf(1.0f + 0.3275911f * ax);
    float poly = t * (0.254829592f +
                 t * (-0.284496736f +
                 t * (1.421413741f +
                 t * (-1.453152027f +
                 t * 1.061405429f))));
    float erfv = 1.0f - poly * __expf(-x * x);
    erfv = copysignf(erfv, x);
    return 0.5f * v * (1.0f + erfv);
}

// ---------------- weight prep: fp32 -> bf16, fc2 transposed to [c][e*192+h] ----
__global__ __launch_bounds__(256) void prep_weights(
    const float* __restrict__ fc1w, const float* __restrict__ fc2w,
    __hip_bfloat16* __restrict__ b1, __hip_bfloat16* __restrict__ b2t)
{
    int idx = blockIdx.x * 256 + threadIdx.x;
    if (idx >= 768 * 768) return;
    // b1[n][k] = fc1_w[e][h][c] with n=e*192+h, k=c  -> flat identity
    b1[idx] = __float2bfloat16(fc1w[idx]);
    // b2t[c][e*192+h] = fc2_w[e][c][h]
    int c = idx / 768;
    int r = idx - c * 768;
    int e = r / 192;
    int h = r - e * 192;
    b2t[idx] = __float2bfloat16(fc2w[((size_t)e * 768 + c) * 192 + h]);
}

// ---------------- router + x fp32->bf16 conversion: one wave per token --------
__global__ __launch_bounds__(256) void router_convert(
    const float* __restrict__ x, const float* __restrict__ rw,
    const float* __restrict__ rb,
    __hip_bfloat16* __restrict__ xb, float* __restrict__ comb)
{
    int wave = threadIdx.x >> 6;
    int lane = threadIdx.x & 63;
    int token = blockIdx.x * 4 + wave;

    const float* xr = x + (size_t)token * CDIM + lane * 12;
    float4 v0 = *(const float4*)(xr);
    float4 v1 = *(const float4*)(xr + 4);
    float4 v2 = *(const float4*)(xr + 8);

    // convert + store bf16 copy of x
    float vals[12];
    *(float4*)(vals) = v0; *(float4*)(vals + 4) = v1; *(float4*)(vals + 8) = v2;
    alignas(16) __hip_bfloat16 hb[12];
#pragma unroll
    for (int j = 0; j < 12; ++j) hb[j] = __float2bfloat16(vals[j]);
    u16x4* dst = (u16x4*)((unsigned short*)xb + (size_t)token * CDIM + lane * 12);
    dst[0] = ((u16x4*)hb)[0];
    dst[1] = ((u16x4*)hb)[1];
    dst[2] = ((u16x4*)hb)[2];

    // router logits: 4 dots of length 768 (fp32, matches reference precision)
    float s[4];
#pragma unroll
    for (int e = 0; e < 4; ++e) {
        const float* w = rw + e * CDIM + lane * 12;
        float4 w0 = *(const float4*)(w);
        float4 w1 = *(const float4*)(w + 4);
        float4 w2 = *(const float4*)(w + 8);
        s[e] = v0.x * w0.x + v0.y * w0.y + v0.z * w0.z + v0.w * w0.w
             + v1.x * w1.x + v1.y * w1.y + v1.z * w1.z + v1.w * w1.w
             + v2.x * w2.x + v2.y * w2.y + v2.z * w2.z + v2.w * w2.w;
    }
#pragma unroll
    for (int e = 0; e < 4; ++e) {
        float v = s[e];
        v += __shfl_xor(v, 32); v += __shfl_xor(v, 16); v += __shfl_xor(v, 8);
        v += __shfl_xor(v, 4);  v += __shfl_xor(v, 2);  v += __shfl_xor(v, 1);
        s[e] = v;
    }
    // softmax over 4 + top-2 + renormalize (all lanes compute, lane 0 writes)
    float lg[4], p[4];
#pragma unroll
    for (int e = 0; e < 4; ++e) lg[e] = s[e] + rb[e];
    float mx = fmaxf(fmaxf(lg[0], lg[1]), fmaxf(lg[2], lg[3]));
    float ps = 0.f;
#pragma unroll
    for (int e = 0; e < 4; ++e) { p[e] = __expf(lg[e] - mx); ps += p[e]; }
#pragma unroll
    for (int e = 0; e < 4; ++e) p[e] /= ps;
    int a = 0;
#pragma unroll
    for (int e = 1; e < 4; ++e) if (p[e] > p[a]) a = e;   // ties -> first (jax)
    int b = (a == 0) ? 1 : 0;
#pragma unroll
    for (int e = 0; e < 4; ++e) if (e != a && p[e] > p[b]) b = e;
    float wsum = p[a] + p[b] + 1e-8f;
    float cb[4] = {0.f, 0.f, 0.f, 0.f};
    cb[a] = p[a] / wsum;
    cb[b] = p[b] / wsum;
    if (lane == 0) {
        float4 o; o.x = cb[0]; o.y = cb[1]; o.z = cb[2]; o.w = cb[3];
        *(float4*)(comb + (size_t)token * 4) = o;
    }
}

// ---------------- GEMM C = A[M x K] * Bt[N x K]^T with fused MoE epilogues ----
// m97 staging + XCD-aware swizzle + XOR'd LDS granules + 1-deep dbuf prefetch.
// MODE 0: fc1  -> hw[t][n] = bf16( gelu(acc + fc1_b[n]) * combine[t][n/192] )
//   NOTE: wave's 64-col footprint lies inside one expert (64 | cols, 192=3*64)
//   -> expert id is wave-uniform; comb read once per output row.
// MODE 1: fc2  -> out[t][c] = acc + sum_e combine[t][e] * fc2_b[e][c]
#define BM 128
#define BN 128
#define BK 64

template <int MODE, int K>
__global__ __launch_bounds__(256) void gemm_bt(
    const __hip_bfloat16* __restrict__ A, const __hip_bfloat16* __restrict__ Bt,
    const float* __restrict__ comb,
    const float* __restrict__ bias1,   // fc1_b flat [768] (MODE 0)
    const float* __restrict__ bias2,   // fc2_b [4][768]   (MODE 1)
    __hip_bfloat16* __restrict__ HW,   // MODE 0 output
    float* __restrict__ OUT)           // MODE 1 output
{
    // two (A,B) buffers: buf b at smem + b*2*BM*BK; 64 KB total.
    // 16B granule g of row r lives at physical granule g ^ (r & 7).
    __shared__ __hip_bfloat16 smem[BM * BK * 4];

    const int tid = threadIdx.x;
    const int wave = tid >> 6, lane = tid & 63;
    const int wm = (wave >> 1) * 64, wn = (wave & 1) * 64;
    const int lrow = lane & 15, quad = lane >> 4;

    // XCD-aware swizzle: flat grid 1536 = 8 XCDs x 32 M-tiles x 6 N-tiles.
    const int g = blockIdx.x;
    const int xcd = g & 7;
    const int slot = g >> 3;            // 0..191
    const int byg = slot / 6;           // 0..31
    const int bx = slot - byg * 6;      // 0..5
    const int by = (xcd << 5) + byg;    // 0..255
    const int rowB0 = bx * BN;
    const int rowA0 = by * BM;

    const int srow = lane >> 3;                 // 0..7 row within chunk
    const int scol = ((lane & 7) ^ srow) * 8;   // source granule (elements)

    // strength-reduced staging addresses: per-p global element offsets
    // (row*K + scol, loop-invariant) and constant LDS chunk bases.
    size_t aoff[4];
    __hip_bfloat16* ldsA[4];
#pragma unroll
    for (int p = 0; p < 4; ++p) {
        int c = wave * 4 + p;
        aoff[p] = (size_t)(c * 8 + srow) * K + scol;
        ldsA[p] = smem + c * 8 * BK;
    }
    const __hip_bfloat16* Abase = A + (size_t)rowA0 * K;
    const __hip_bfloat16* Bbase = Bt + (size_t)rowB0 * K;

    auto stage = [&](int buf, int k0) {
        int boff = buf * (2 * BM * BK);
#pragma unroll
        for (int p = 0; p < 4; ++p) {
            async_copy16(Abase + aoff[p] + k0, ldsA[p] + boff);
            async_copy16(Bbase + aoff[p] + k0, ldsA[p] + boff + BM * BK);
        }
    };

    f32x4 acc[4][4] = {};
    constexpr int NIT = K / BK;     // 12

    stage(0, 0);
    __syncthreads();
#pragma unroll
    for (int it = 0; it < NIT; ++it) {
        if (it + 1 < NIT) stage((it + 1) & 1, (it + 1) * BK);  // prefetch in flight
        const __hip_bfloat16* As = smem + (it & 1) * (2 * BM * BK);
        const __hip_bfloat16* Bs = As + BM * BK;
#pragma unroll
        for (int kk = 0; kk < BK; kk += 32) {
            bf16x8 af[4], bfr[4];
#pragma unroll
            for (int i = 0; i < 4; ++i) {
                int row = wm + i * 16 + lrow;
                int gp = ((kk >> 3) + quad) ^ (lrow & 7);
                af[i] = *(const bf16x8*)(&As[row * BK + gp * 8]);
            }
#pragma unroll
            for (int j = 0; j < 4; ++j) {
                int row = wn + j * 16 + lrow;
                int gp = ((kk >> 3) + quad) ^ (lrow & 7);
                bfr[j] = *(const bf16x8*)(&Bs[row * BK + gp * 8]);
            }
#pragma unroll
            for (int i = 0; i < 4; ++i)
#pragma unroll
                for (int j = 0; j < 4; ++j)
                    acc[i][j] = __builtin_amdgcn_mfma_f32_16x16x32_bf16(
                        af[i], bfr[j], acc[i][j], 0, 0, 0);
        }
        __syncthreads();   // drains prefetch (vmcnt 0) + guards LDS reuse
    }

    // epilogue; C/D layout: col = lane&15, row = quad*4 + reg  [verified m89/m91]
    if (MODE == 0) {
        const int e = (rowB0 + wn) / 192;          // wave-uniform expert id
        const float* combE = comb + (size_t)rowA0 * 4 + e;
        float b1v[4];
#pragma unroll
        for (int j = 0; j < 4; ++j) b1v[j] = bias1[rowB0 + wn + j * 16 + lrow];
#pragma unroll
        for (int i = 0; i < 4; ++i) {
#pragma unroll
            for (int r = 0; r < 4; ++r) {
                int rowl = wm + i * 16 + quad * 4 + r;
                float c = combE[rowl * 4];
                __hip_bfloat16* srow_p = &smem[rowl * BN + wn + lrow];
#pragma unroll
                for (int j = 0; j < 4; ++j) {
                    float v = fast_gelu(acc[i][j][r] + b1v[j]) * c;
                    srow_p[j * 16] = __float2bfloat16(v);
                }
            }
        }
        __syncthreads();
        // 128 rows x 256 B; 2048 uint4 chunks over 256 threads = 8 each
#pragma unroll
        for (int t = 0; t < 8; ++t) {
            int idx = t * 256 + tid;
            int row = idx >> 4;            // 0..127
            int c16 = (idx & 15) * 8;      // element col, 16B granules
            *(uint4*)(HW + (size_t)(rowA0 + row) * NKDIM + rowB0 + c16) =
                *(const uint4*)(&smem[row * BN + c16]);
        }
    } else {
        // hoist fc2 bias gathers: 16 scalar loads total (vs 256 in-loop)
        float4 bbv[4];
#pragma unroll
        for (int j = 0; j < 4; ++j) {
            int col = rowB0 + wn + j * 16 + lrow;
            bbv[j].x = bias2[col];
            bbv[j].y = bias2[768 + col];
            bbv[j].z = bias2[1536 + col];
            bbv[j].w = bias2[2304 + col];
        }
#pragma unroll
        for (int i = 0; i < 4; ++i) {
#pragma unroll
            for (int r = 0; r < 4; ++r) {
                int row = rowA0 + wm + i * 16 + quad * 4 + r;
                float4 cw = *(const float4*)(comb + (size_t)row * 4);
                float* orow = OUT + (size_t)row * CDIM + rowB0 + wn + lrow;
#pragma unroll
                for (int j = 0; j < 4; ++j) {
                    float v = acc[i][j][r]
                            + cw.x * bbv[j].x + cw.y * bbv[j].y
                            + cw.z * bbv[j].z + cw.w * bbv[j].w;
                    orow[j * 16] = v;
                }
            }
        }
    }
}

extern "C" void kernel_launch(void* const* d_in, const int* in_sizes, int n_in,
                              void* d_out, int out_size, void* d_ws, size_t ws_size,
                              hipStream_t stream)
{
    const float* x    = (const float*)d_in[0];
    const float* rw   = (const float*)d_in[1];
    const float* rb   = (const float*)d_in[2];
    const float* fc1w = (const float*)d_in[3];
    const float* fc1b = (const float*)d_in[4];
    const float* fc2w = (const float*)d_in[5];
    const float* fc2b = (const float*)d_in[6];
    float* out = (float*)d_out;

    // workspace layout (bytes), all 16B-aligned; total ~103.6 MB
    char* ws = (char*)d_ws;
    __hip_bfloat16* xb  = (__hip_bfloat16*)(ws);                 // 32768*768*2 = 50331648
    __hip_bfloat16* hw  = (__hip_bfloat16*)(ws + 50331648);      // 50331648
    __hip_bfloat16* b1  = (__hip_bfloat16*)(ws + 100663296);     // 1179648
    __hip_bfloat16* b2t = (__hip_bfloat16*)(ws + 101842944);     // 1179648
    float*          cmb = (float*)        (ws + 103022592);      // 524288

    prep_weights<<<2304, 256, 0, stream>>>(fc1w, fc2w, b1, b2t);
    router_convert<<<TOKENS / 4, 256, 0, stream>>>(x, rw, rb, xb, cmb);

    int nblocks = (NKDIM / BN) * (TOKENS / BM);   // 1536, XCD-swizzled in-kernel
    gemm_bt<0, CDIM><<<nblocks, 256, 0, stream>>>(xb, b1, cmb, fc1b, nullptr, hw, nullptr);
    gemm_bt<1, NKDIM><<<nblocks, 256, 0, stream>>>(hw, b2t, cmb, nullptr, fc2b, nullptr, out);
}